// Round 2
// baseline (425.784 us; speedup 1.0000x reference)
//
#include <hip/hip_runtime.h>
#include <hip/hip_bf16.h>

typedef __hip_bfloat16 bf16;
typedef __attribute__((ext_vector_type(8))) __bf16 bfrag;   // MFMA A/B operand
typedef __attribute__((ext_vector_type(4))) float f32x4;    // MFMA C/D

#define N_NODES 50000
#define N_EDGES 800000
#define GB_GEMM 782            // 2 col-tiles x 391 row-tiles (layer-1 GEMM)
#define GB_PLACE 3125          // ceil(800000/256)

__device__ __forceinline__ unsigned short f2bf(float f) {
    bf16 h = __float2bfloat16(f);
    return *reinterpret_cast<unsigned short*>(&h);
}

__device__ __forceinline__ uint4 zero4() { uint4 z; z.x = z.y = z.z = z.w = 0u; return z; }

// int64 path: load the full 8B element (coalesced, 100% line use).
__device__ __forceinline__ void load_edge(const int* __restrict__ ei, int fl64,
                                          int e, int& s, int& d) {
    if (fl64) {
        int2 a = ((const int2*)ei)[e];
        int2 b = ((const int2*)ei)[N_EDGES + e];
        s = a.x; d = b.x;
    } else {
        s = ei[e];
        d = ei[N_EDGES + e];
    }
}

__device__ __forceinline__ float rdf(const void* p, int off, int f32) {
    return f32 ? ((const float*)p)[off] : (float)((const bf16*)p)[off];
}

// ---------------------------------------------------------------------------
// detect + zero: block 0 detects dtypes (flags), all 391 blocks zero cntS/cntD.
// ---------------------------------------------------------------------------
__global__ void detect_zero_kernel(const unsigned short* __restrict__ xb,
                                   const int* __restrict__ ei,
                                   int* __restrict__ flags,
                                   int* __restrict__ cnt) {   // 2*N_NODES ints
    int i = blockIdx.x * 256 + threadIdx.x;
    if (i < 2 * N_NODES) cnt[i] = 0;
    if (blockIdx.x == 0) {
        __shared__ int s_insane, s_nonzero;
        int t = threadIdx.x;
        if (t == 0) { s_insane = 0; s_nonzero = 0; }
        __syncthreads();
        unsigned short h = xb[2 * t];
        int e = (h >> 7) & 0xFF;
        if (!(e == 0 || (e >= 90 && e <= 150))) atomicOr(&s_insane, 1);
        if (ei[2 * t + 1] != 0) atomicOr(&s_nonzero, 1);
        __syncthreads();
        if (t == 0) { flags[0] = s_insane ? 1 : 0; flags[1] = s_nonzero ? 0 : 1; }
    }
}

// ---------------------------------------------------------------------------
// Unified weight/bias conversion.
//  [0,163840):        conv WT bf16 transposed [N][256] (W1 N=256, W2 N=256, W3 N=128)
//  [163840,172032):   mWT1 bf16 [64][128]
//  [172032,176128):   mWT2 bf16 [64][64]
//  [176128,176896):   biases fp32: b1(256) b2(256) b3(128) mb1(64) mb2(64)
// ---------------------------------------------------------------------------
__global__ void cvt_all_kernel(const void* W1, const void* W2, const void* W3,
                               const void* mW1, const void* mW2,
                               const void* b1, const void* b2, const void* b3,
                               const void* mb1, const void* mb2,
                               const int* __restrict__ flags,
                               unsigned short* __restrict__ WT,
                               float* __restrict__ biasd) {
    int i = blockIdx.x * 256 + threadIdx.x;
    if (i >= 176896) return;
    const int f32 = flags[0];
    if (i < 163840) {
        const void* s; int local, N;
        if      (i <  65536) { s = W1; local = i;          N = 256; }
        else if (i < 131072) { s = W2; local = i -  65536; N = 256; }
        else                 { s = W3; local = i - 131072; N = 128; }
        int n = local >> 8, k = local & 255;
        WT[i] = f2bf(rdf(s, k * N + n, f32));
    } else if (i < 172032) {
        int local = i - 163840;
        int n = local >> 7, k = local & 127;
        WT[i] = f2bf(rdf(mW1, k * 64 + n, f32));
    } else if (i < 176128) {
        int local = i - 172032;
        int n = local >> 6, k = local & 63;
        WT[i] = f2bf(rdf(mW2, k * 64 + n, f32));
    } else {
        int local = i - 176128;
        const void* s; int off;
        if      (local < 256) { s = b1;  off = local; }
        else if (local < 512) { s = b2;  off = local - 256; }
        else if (local < 640) { s = b3;  off = local - 512; }
        else if (local < 704) { s = mb1; off = local - 640; }
        else                  { s = mb2; off = local - 704; }
        biasd[local] = rdf(s, off, f32);
    }
}

// ---------------------------------------------------------------------------
// Staging row loaders: bf16 passthrough, or fp32 load + pack to bf16.
// ---------------------------------------------------------------------------
__device__ __forceinline__ uint4 ld8_bf16(const unsigned short* p) {
    return *(const uint4*)p;
}
__device__ __forceinline__ uint4 ld8_f32(const float* p) {
    float4 a = *(const float4*)(p);
    float4 b = *(const float4*)(p + 4);
    uint4 r;
    r.x = ((unsigned)f2bf(a.y) << 16) | f2bf(a.x);
    r.y = ((unsigned)f2bf(a.w) << 16) | f2bf(a.z);
    r.z = ((unsigned)f2bf(b.y) << 16) | f2bf(b.x);
    r.w = ((unsigned)f2bf(b.w) << 16) | f2bf(b.z);
    return r;
}

// ---------------------------------------------------------------------------
// Conv GEMM body (layer-1 only now): C_bf16[M][N] = bf16(X @ W), fp32 accum,
// K=256, 128x128 tile, 4 waves x (4x4) 16x16x32 MFMA.  Unscaled output (the
// sOut scale is applied per-edge in fconv's gather, since cntS is built
// concurrently with this GEMM).
// ---------------------------------------------------------------------------
template <bool DUALX>
__device__ __forceinline__ void gemm_body(
        unsigned short (*Xs)[40], unsigned short (*Ws)[40],
        const void* __restrict__ Xv, const int* __restrict__ flags,
        const unsigned short* __restrict__ WT,
        unsigned short* __restrict__ C,
        int bx, int by, int M, int N) {
    constexpr int K = 256;
    const int tid  = threadIdx.x;
    const int lane = tid & 63;
    const int w    = tid >> 6;
    const int wr   = (w >> 1) * 64;
    const int wc   = (w & 1) * 64;
    const int lrow = lane & 15;
    const int koff = (lane >> 4) * 8;
    const int row0 = by * 128;
    const int col0 = bx * 128;
    const bool xf32 = DUALX && (flags[0] != 0);
    const unsigned short* Xb = (const unsigned short*)Xv;
    const float* Xf = (const float*)Xv;

    const int r0 = tid >> 2, q0 = tid & 3;
    const int r1 = r0 + 64;
    const int gr0 = row0 + r0, gr1 = row0 + r1;

    uint4 xv0, xv1, wv0, wv1;
    {
        int e = q0 * 8;
        xv0 = (gr0 < M) ? (xf32 ? ld8_f32(Xf + (size_t)gr0 * K + e)
                                : ld8_bf16(Xb + (size_t)gr0 * K + e)) : zero4();
        xv1 = (gr1 < M) ? (xf32 ? ld8_f32(Xf + (size_t)gr1 * K + e)
                                : ld8_bf16(Xb + (size_t)gr1 * K + e)) : zero4();
        wv0 = *(const uint4*)(WT + (size_t)(col0 + r0) * K + e);
        wv1 = *(const uint4*)(WT + (size_t)(col0 + r1) * K + e);
    }

    f32x4 acc[4][4] = {};

    for (int k0 = 0; k0 < K; k0 += 32) {
        *(uint4*)&Xs[r0][q0 * 8] = xv0;
        *(uint4*)&Xs[r1][q0 * 8] = xv1;
        *(uint4*)&Ws[r0][q0 * 8] = wv0;
        *(uint4*)&Ws[r1][q0 * 8] = wv1;
        __syncthreads();

        const int k1 = k0 + 32;
        if (k1 < K) {
            int e = k1 + q0 * 8;
            xv0 = (gr0 < M) ? (xf32 ? ld8_f32(Xf + (size_t)gr0 * K + e)
                                    : ld8_bf16(Xb + (size_t)gr0 * K + e)) : zero4();
            xv1 = (gr1 < M) ? (xf32 ? ld8_f32(Xf + (size_t)gr1 * K + e)
                                    : ld8_bf16(Xb + (size_t)gr1 * K + e)) : zero4();
            wv0 = *(const uint4*)(WT + (size_t)(col0 + r0) * K + e);
            wv1 = *(const uint4*)(WT + (size_t)(col0 + r1) * K + e);
        }

        bfrag af[4], bv[4];
#pragma unroll
        for (int i = 0; i < 4; i++)
            af[i] = *(const bfrag*)&Xs[wr + i * 16 + lrow][koff];
#pragma unroll
        for (int j = 0; j < 4; j++)
            bv[j] = *(const bfrag*)&Ws[wc + j * 16 + lrow][koff];
#pragma unroll
        for (int i = 0; i < 4; i++)
#pragma unroll
            for (int j = 0; j < 4; j++)
                acc[i][j] = __builtin_amdgcn_mfma_f32_16x16x32_bf16(
                    af[i], bv[j], acc[i][j], 0, 0, 0);
        __syncthreads();
    }

#pragma unroll
    for (int i = 0; i < 4; i++) {
#pragma unroll
        for (int r = 0; r < 4; r++) {
            int row = row0 + wr + i * 16 + ((lane >> 4) * 4) + r;
            if (row >= M) continue;
#pragma unroll
            for (int j = 0; j < 4; j++) {
                int col = col0 + wc + j * 16 + lrow;
                C[(size_t)row * N + col] = f2bf(acc[i][j][r]);
            }
        }
    }
}

// ---------------------------------------------------------------------------
// Mega kernel A: blocks [0,GB_GEMM) = layer-1 GEMM tiles (CSR-independent),
// blocks [GB_GEMM, GB_GEMM+GB_PLACE) = one-pass padded-CSR build.
// ---------------------------------------------------------------------------
__launch_bounds__(256)
__global__ void megaA_kernel(const void* __restrict__ x,
                             const int* __restrict__ ei,
                             const int* __restrict__ flags,
                             const unsigned short* __restrict__ WT,
                             unsigned short* __restrict__ Hbf,
                             int* __restrict__ cntS, int* __restrict__ cntD,
                             unsigned short* __restrict__ esrc_pad, int M) {
    __shared__ unsigned short Xs[128][40];
    __shared__ unsigned short Ws[128][40];
    const int bid = blockIdx.x;
    if (bid < GB_GEMM) {
        gemm_body<true>(Xs, Ws, x, flags, WT, Hbf, bid & 1, bid >> 1, M, 256);
    } else {
        int e = (bid - GB_GEMM) * 256 + threadIdx.x;
        if (e < N_EDGES) {
            int s, d; load_edge(ei, flags[1], e, s, d);
            atomicAdd(&cntS[s], 1);
            int pos = atomicAdd(&cntD[d], 1);
            if (pos < 64)
                __builtin_nontemporal_store((unsigned short)s,
                                            &esrc_pad[(d << 6) + pos]);
        }
    }
}

// ---------------------------------------------------------------------------
// Gather accumulation helper: sum over a node's padded src list.
// ESCALE: apply per-edge rsqrt(outdeg) (only needed for layer-1 source,
// whose H was written before counts were final).  Layers 2/3 sources are
// pre-scaled at GEMM-epilogue time -> pure sum, no random 4B scale loads.
// ---------------------------------------------------------------------------
__device__ __forceinline__ void accs(unsigned int u, float s, float& a0, float& a1) {
    a0 = fmaf(s, __uint_as_float(u << 16), a0);
    a1 = fmaf(s, __uint_as_float(u & 0xffff0000u), a1);
}
__device__ __forceinline__ void acc4s(uint4 u, float s, float (&a)[8]) {
    accs(u.x, s, a[0], a[1]); accs(u.y, s, a[2], a[3]);
    accs(u.z, s, a[4], a[5]); accs(u.w, s, a[6], a[7]);
}

template <int LQ, bool ESCALE>
__device__ __forceinline__ void gather_accum(const uint4* __restrict__ H4,
                                             const unsigned short* __restrict__ ep,
                                             const int* __restrict__ cntS,
                                             int cn, int lane, float (&a)[8]) {
    int j = 0;
    for (; j + 4 <= cn; j += 4) {
        int s0 = ep[j], s1 = ep[j + 1], s2 = ep[j + 2], s3 = ep[j + 3];
        float w0 = 1.f, w1 = 1.f, w2 = 1.f, w3 = 1.f;
        if (ESCALE) {
            w0 = rsqrtf((float)max(cntS[s0], 1));
            w1 = rsqrtf((float)max(cntS[s1], 1));
            w2 = rsqrtf((float)max(cntS[s2], 1));
            w3 = rsqrtf((float)max(cntS[s3], 1));
        }
        uint4 u0 = H4[(size_t)s0 * LQ + lane];
        uint4 u1 = H4[(size_t)s1 * LQ + lane];
        uint4 u2 = H4[(size_t)s2 * LQ + lane];
        uint4 u3 = H4[(size_t)s3 * LQ + lane];
        acc4s(u0, w0, a); acc4s(u1, w1, a);
        acc4s(u2, w2, a); acc4s(u3, w3, a);
    }
    for (; j < cn; j++) {
        int s0 = ep[j];
        float w0 = ESCALE ? rsqrtf((float)max(cntS[s0], 1)) : 1.f;
        uint4 u = H4[(size_t)s0 * LQ + lane];
        acc4s(u, w0, a);
    }
}

// ---------------------------------------------------------------------------
// Fused gather + conv-GEMM.  Block owns 32 output rows [32b, 32b+32):
//   phase 1: gather those 32 nodes' aggregates from H (D=256), apply
//            sIn*relu(.+bias), write bf16 rows into LDS Xf.  (The GEMM
//            row-tile needs exactly these rows -> no cross-block dep, and
//            the activation never round-trips through HBM.)
//   phase 2: 8 waves MFMA  Xf[32x256] @ WTn^T -> 32 x NOUT, B-fragments read
//            DIRECTLY from global WT (131KB, L2-resident; no LDS staging).
//   epilogue: pre-scale row by rsqrt(outdeg[row]) so the NEXT gather is a
//            pure sum, then store bf16.
// ---------------------------------------------------------------------------
template <int NOUT, bool ESCALE>
__launch_bounds__(512)
__global__ void fconv_kernel(const unsigned short* __restrict__ H,    // [M][256]
                             const int* __restrict__ cntD,
                             const int* __restrict__ cntS,
                             const unsigned short* __restrict__ esrc_pad,
                             const float* __restrict__ bias,          // [256]
                             const unsigned short* __restrict__ WTn,  // [NOUT][256]
                             unsigned short* __restrict__ Hout,       // [M][NOUT]
                             int M) {
    __shared__ unsigned short Xf[32][264];    // stride 528B -> bank step 4, 2-way max
    const int tid = threadIdx.x;
    const int row0 = blockIdx.x * 32;

    // ---- phase 1: gather (16 node-slots x 32 lanes, 2 rounds) ----
    {
        const int slot = tid >> 5;
        const int gl   = tid & 31;
        const uint4* H4 = (const uint4*)H;
        const float* bp = bias + gl * 8;
        float4 b0 = *(const float4*)(bp);
        float4 b1 = *(const float4*)(bp + 4);
#pragma unroll
        for (int round = 0; round < 2; ++round) {
            const int node = row0 + round * 16 + slot;
            float a[8] = {};
            float sc = 0.f;
            if (node < M) {
                const unsigned short* ep = esrc_pad + (node << 6);
                const int cn = min(cntD[node], 64);
                gather_accum<32, ESCALE>(H4, ep, cntS, cn, gl, a);
                sc = rsqrtf((float)max(cntD[node], 1));
            }
            ushort4 o0, o1;
            o0.x = f2bf(fmaxf(fmaf(a[0], sc, b0.x), 0.f));
            o0.y = f2bf(fmaxf(fmaf(a[1], sc, b0.y), 0.f));
            o0.z = f2bf(fmaxf(fmaf(a[2], sc, b0.z), 0.f));
            o0.w = f2bf(fmaxf(fmaf(a[3], sc, b0.w), 0.f));
            o1.x = f2bf(fmaxf(fmaf(a[4], sc, b1.x), 0.f));
            o1.y = f2bf(fmaxf(fmaf(a[5], sc, b1.y), 0.f));
            o1.z = f2bf(fmaxf(fmaf(a[6], sc, b1.z), 0.f));
            o1.w = f2bf(fmaxf(fmaf(a[7], sc, b1.w), 0.f));
            *(ushort4*)&Xf[round * 16 + slot][gl * 8]     = o0;
            *(ushort4*)&Xf[round * 16 + slot][gl * 8 + 4] = o1;
        }
    }
    __syncthreads();

    // ---- phase 2: GEMM 32 x NOUT, K=256 ----
    const int lane = tid & 63;
    const int w    = tid >> 6;
    const int lrow = lane & 15;
    const int koff = (lane >> 4) * 8;
    const int wr   = (w >> 2) * 16;                 // {0,16}
    constexpr int NJ = (NOUT == 256) ? 4 : 2;
    const int wc   = (w & 3) * (NJ * 16);           // covers NOUT
    f32x4 acc[NJ] = {};
#pragma unroll 2
    for (int k0 = 0; k0 < 256; k0 += 32) {
        const bfrag af = *(const bfrag*)&Xf[wr + lrow][k0 + koff];
#pragma unroll
        for (int j = 0; j < NJ; j++) {
            const bfrag bv = *(const bfrag*)&WTn[(size_t)(wc + j * 16 + lrow) * 256
                                                 + k0 + koff];
            acc[j] = __builtin_amdgcn_mfma_f32_16x16x32_bf16(af, bv, acc[j], 0, 0, 0);
        }
    }
#pragma unroll
    for (int r = 0; r < 4; r++) {
        const int rl = wr + (lane >> 4) * 4 + r;
        const int grow = row0 + rl;
        if (grow >= M) continue;
        const float s = rsqrtf((float)max(cntS[grow], 1));   // pre-scale for next gather
#pragma unroll
        for (int j = 0; j < NJ; j++)
            Hout[(size_t)grow * NOUT + wc + j * 16 + lrow] = f2bf(acc[j][r] * s);
    }
}

// ---------------------------------------------------------------------------
// Fused final gather (D=128, pre-scaled source -> pure sum) + 2-layer MLP.
//   phase 1: 32 node-slots x 16 lanes, one round; result IS h_last ->
//            write fp32 out_h + bf16 into LDS.
//   phase 2: relu(Xs @ mW1 + mb1) -> X2 (LDS), then X2 @ mW2 + mb2 -> out.
//            W fragments direct from global (L2-hot, 16KB + 8KB).
// ---------------------------------------------------------------------------
__launch_bounds__(512)
__global__ void fmlp_kernel(const unsigned short* __restrict__ H3,   // [M][128]
                            const int* __restrict__ cntD,
                            const unsigned short* __restrict__ esrc_pad,
                            const float* __restrict__ b3,
                            const float* __restrict__ mb1,
                            const float* __restrict__ mb2,
                            const unsigned short* __restrict__ WT1,  // [64][128]
                            const unsigned short* __restrict__ WT2,  // [64][64]
                            float* __restrict__ out,                 // [M][64]
                            float* __restrict__ outh,                // [M][128]
                            int M) {
    __shared__ unsigned short Xs[32][136];
    __shared__ unsigned short X2[32][72];
    const int tid = threadIdx.x;
    const int row0 = blockIdx.x * 32;

    // ---- phase 1: gather h_last ----
    {
        const int slot = tid >> 4;     // 32 nodes
        const int gl   = tid & 15;     // LQ=16
        const uint4* H4 = (const uint4*)H3;
        const int node = row0 + slot;
        float a[8] = {};
        float sc = 0.f;
        if (node < M) {
            const unsigned short* ep = esrc_pad + (node << 6);
            const int cn = min(cntD[node], 64);
            gather_accum<16, false>(H4, ep, nullptr, cn, gl, a);
            sc = rsqrtf((float)max(cntD[node], 1));
        }
        const float* bp = b3 + gl * 8;
        float4 b0 = *(const float4*)(bp);
        float4 b1 = *(const float4*)(bp + 4);
        float r0 = fmaxf(fmaf(a[0], sc, b0.x), 0.f);
        float r1 = fmaxf(fmaf(a[1], sc, b0.y), 0.f);
        float r2 = fmaxf(fmaf(a[2], sc, b0.z), 0.f);
        float r3 = fmaxf(fmaf(a[3], sc, b0.w), 0.f);
        float r4 = fmaxf(fmaf(a[4], sc, b1.x), 0.f);
        float r5 = fmaxf(fmaf(a[5], sc, b1.y), 0.f);
        float r6 = fmaxf(fmaf(a[6], sc, b1.z), 0.f);
        float r7 = fmaxf(fmaf(a[7], sc, b1.w), 0.f);
        if (node < M) {
            float* yp = outh + (size_t)node * 128 + gl * 8;
            float4 o0 = {r0, r1, r2, r3};
            float4 o1 = {r4, r5, r6, r7};
            *(float4*)(yp)     = o0;
            *(float4*)(yp + 4) = o1;
        }
        ushort4 o0, o1;
        o0.x = f2bf(r0); o0.y = f2bf(r1); o0.z = f2bf(r2); o0.w = f2bf(r3);
        o1.x = f2bf(r4); o1.y = f2bf(r5); o1.z = f2bf(r6); o1.w = f2bf(r7);
        *(ushort4*)&Xs[slot][gl * 8]     = o0;
        *(ushort4*)&Xs[slot][gl * 8 + 4] = o1;
    }
    __syncthreads();

    // ---- phase 2a: relu(Xs @ mW1 + mb1) -> X2 ----
    const int lane = tid & 63;
    const int w    = tid >> 6;
    const int lrow = lane & 15;
    const int koff = (lane >> 4) * 8;
    const int wr   = (w >> 2) * 16;     // {0,16}
    const int wc   = (w & 3) * 16;      // {0,16,32,48}
    f32x4 acc = {};
#pragma unroll
    for (int k0 = 0; k0 < 128; k0 += 32) {
        const bfrag af = *(const bfrag*)&Xs[wr + lrow][k0 + koff];
        const bfrag bv = *(const bfrag*)&WT1[(size_t)(wc + lrow) * 128 + k0 + koff];
        acc = __builtin_amdgcn_mfma_f32_16x16x32_bf16(af, bv, acc, 0, 0, 0);
    }
#pragma unroll
    for (int r = 0; r < 4; r++) {
        const int rl  = wr + (lane >> 4) * 4 + r;
        const int col = wc + lrow;
        X2[rl][col] = f2bf(fmaxf(acc[r] + mb1[col], 0.f));
    }
    __syncthreads();

    // ---- phase 2b: X2 @ mW2 + mb2 -> out ----
    f32x4 acc2 = {};
#pragma unroll
    for (int k0 = 0; k0 < 64; k0 += 32) {
        const bfrag af = *(const bfrag*)&X2[wr + lrow][k0 + koff];
        const bfrag bv = *(const bfrag*)&WT2[(size_t)(wc + lrow) * 64 + k0 + koff];
        acc2 = __builtin_amdgcn_mfma_f32_16x16x32_bf16(af, bv, acc2, 0, 0, 0);
    }
#pragma unroll
    for (int r = 0; r < 4; r++) {
        const int rl   = wr + (lane >> 4) * 4 + r;
        const int grow = row0 + rl;
        if (grow >= M) continue;
        out[(size_t)grow * 64 + wc + lrow] = acc2[r] + mb2[wc + lrow];
    }
}

// ---------------------------------------------------------------------------
extern "C" void kernel_launch(void* const* d_in, const int* in_sizes, int n_in,
                              void* d_out, int out_size, void* d_ws, size_t ws_size,
                              hipStream_t stream) {
    const void* x  = d_in[0];
    const int*  ei = (const int*)d_in[1];
    const void *W1 = d_in[2],  *b1 = d_in[3];
    const void *W2 = d_in[4],  *b2 = d_in[5];
    const void *W3 = d_in[6],  *b3 = d_in[7];
    const void *mW1 = d_in[8], *mb1 = d_in[9];
    const void *mW2 = d_in[10],*mb2 = d_in[11];

    // Output: fp32 concatenated (out[50000x64], h_last[50000x128])
    float* out   = (float*)d_out;
    float* out_h = out + (size_t)N_NODES * 64;

    float* ws = (float*)d_ws;
    size_t off = 0;
    int*   flags  = (int*)(ws + off); off += 64;
    int*   cntS   = (int*)(ws + off); off += N_NODES;        // zeroed together
    int*   cntD   = (int*)(ws + off); off += N_NODES;
    unsigned short* esrc_p = (unsigned short*)(ws + off);
    off += (size_t)N_NODES * 32;                             // 50000*64 ushorts
    float* biasd  = ws + off;         off += 768;
    // bias offsets: b1@0 b2@256 b3@512 mb1@640 mb2@704
    off = (off + 63) & ~(size_t)63;
    unsigned short* WT  = (unsigned short*)(ws + off); off += 88448;  // 176896 u16
    // WT segments: conv@0 (W1,W2,W3), mWT1@163840, mWT2@172032
    unsigned short* Hbf = (unsigned short*)(ws + off); off += (size_t)N_NODES * 128;
    unsigned short* H2  = (unsigned short*)(ws + off); off += (size_t)N_NODES * 128;
    unsigned short* H3  = Hbf;   // Hbf dead after F1; reuse for the 128-wide H3

    const int M = N_NODES;
    const dim3 blk(256);
    const int g32 = (M + 31) / 32;            // 1563

    // 1) detect + zero counters
    detect_zero_kernel<<<391, blk, 0, stream>>>(
        (const unsigned short*)x, ei, flags, cntS);

    // 2) weight/bias conversion
    cvt_all_kernel<<<(176896 + 255) / 256, blk, 0, stream>>>(
        W1, W2, W3, mW1, mW2, b1, b2, b3, mb1, mb2, flags, WT, biasd);

    // 3) mega A: layer-1 GEMM (x @ W1 -> Hbf, unscaled) || padded-CSR build
    megaA_kernel<<<GB_GEMM + GB_PLACE, blk, 0, stream>>>(
        x, ei, flags, WT, Hbf, cntS, cntD, esrc_p, M);

    // 4) F1: gather(Hbf, per-edge sOut) + GEMM2 -> H2 (pre-scaled by sOut)
    fconv_kernel<256, true><<<g32, dim3(512), 0, stream>>>(
        Hbf, cntD, cntS, esrc_p, biasd, WT + 65536, H2, M);

    // 5) F2: gather(H2, pure sum) + GEMM3 -> H3 (pre-scaled by sOut)
    fconv_kernel<128, false><<<g32, dim3(512), 0, stream>>>(
        H2, cntD, cntS, esrc_p, biasd + 256, WT + 131072, H3, M);

    // 6) F3: gather(H3, pure sum) = h_last -> out_h + fused 2-layer MLP -> out
    fmlp_kernel<<<g32, dim3(512), 0, stream>>>(
        H3, cntD, esrc_p, biasd + 512, biasd + 640, biasd + 704,
        WT + 163840, WT + 172032, out, out_h, M);
}

// Round 3
// 418.176 us; speedup vs baseline: 1.0182x; 1.0182x over previous
//
#include <hip/hip_runtime.h>
#include <hip/hip_bf16.h>

typedef __hip_bfloat16 bf16;
typedef __attribute__((ext_vector_type(8))) __bf16 bfrag;   // MFMA A/B operand
typedef __attribute__((ext_vector_type(4))) float f32x4;    // MFMA C/D

#define N_NODES 50000
#define N_EDGES 800000
#define GB_GEMM 782            // 2 col-tiles x 391 row-tiles (layer-1 GEMM)
#define GB_PLACE 3125          // ceil(800000/256)

__device__ __forceinline__ unsigned short f2bf(float f) {
    bf16 h = __float2bfloat16(f);
    return *reinterpret_cast<unsigned short*>(&h);
}

__device__ __forceinline__ uint4 zero4() { uint4 z; z.x = z.y = z.z = z.w = 0u; return z; }

// int64 path: load the full 8B element (coalesced, 100% line use).
__device__ __forceinline__ void load_edge(const int* __restrict__ ei, int fl64,
                                          int e, int& s, int& d) {
    if (fl64) {
        int2 a = ((const int2*)ei)[e];
        int2 b = ((const int2*)ei)[N_EDGES + e];
        s = a.x; d = b.x;
    } else {
        s = ei[e];
        d = ei[N_EDGES + e];
    }
}

__device__ __forceinline__ float rdf(const void* p, int off, int f32) {
    return f32 ? ((const float*)p)[off] : (float)((const bf16*)p)[off];
}

// ---------------------------------------------------------------------------
// detect + zero: block 0 detects dtypes (flags), all 391 blocks zero cntS/cntD.
// ---------------------------------------------------------------------------
__global__ void detect_zero_kernel(const unsigned short* __restrict__ xb,
                                   const int* __restrict__ ei,
                                   int* __restrict__ flags,
                                   int* __restrict__ cnt) {   // 2*N_NODES ints
    int i = blockIdx.x * 256 + threadIdx.x;
    if (i < 2 * N_NODES) cnt[i] = 0;
    if (blockIdx.x == 0) {
        __shared__ int s_insane, s_nonzero;
        int t = threadIdx.x;
        if (t == 0) { s_insane = 0; s_nonzero = 0; }
        __syncthreads();
        unsigned short h = xb[2 * t];
        int e = (h >> 7) & 0xFF;
        if (!(e == 0 || (e >= 90 && e <= 150))) atomicOr(&s_insane, 1);
        if (ei[2 * t + 1] != 0) atomicOr(&s_nonzero, 1);
        __syncthreads();
        if (t == 0) { flags[0] = s_insane ? 1 : 0; flags[1] = s_nonzero ? 0 : 1; }
    }
}

// ---------------------------------------------------------------------------
// Unified weight/bias conversion.
//  [0,163840):        conv WT bf16 transposed [N][256] (W1 N=256, W2 N=256, W3 N=128)
//  [163840,172032):   mWT1 bf16 [64][128]
//  [172032,176128):   mWT2 bf16 [64][64]
//  [176128,176896):   biases fp32: b1(256) b2(256) b3(128) mb1(64) mb2(64)
// ---------------------------------------------------------------------------
__global__ void cvt_all_kernel(const void* W1, const void* W2, const void* W3,
                               const void* mW1, const void* mW2,
                               const void* b1, const void* b2, const void* b3,
                               const void* mb1, const void* mb2,
                               const int* __restrict__ flags,
                               unsigned short* __restrict__ WT,
                               float* __restrict__ biasd) {
    int i = blockIdx.x * 256 + threadIdx.x;
    if (i >= 176896) return;
    const int f32 = flags[0];
    if (i < 163840) {
        const void* s; int local, N;
        if      (i <  65536) { s = W1; local = i;          N = 256; }
        else if (i < 131072) { s = W2; local = i -  65536; N = 256; }
        else                 { s = W3; local = i - 131072; N = 128; }
        int n = local >> 8, k = local & 255;
        WT[i] = f2bf(rdf(s, k * N + n, f32));
    } else if (i < 172032) {
        int local = i - 163840;
        int n = local >> 7, k = local & 127;
        WT[i] = f2bf(rdf(mW1, k * 64 + n, f32));
    } else if (i < 176128) {
        int local = i - 172032;
        int n = local >> 6, k = local & 63;
        WT[i] = f2bf(rdf(mW2, k * 64 + n, f32));
    } else {
        int local = i - 176128;
        const void* s; int off;
        if      (local < 256) { s = b1;  off = local; }
        else if (local < 512) { s = b2;  off = local - 256; }
        else if (local < 640) { s = b3;  off = local - 512; }
        else if (local < 704) { s = mb1; off = local - 640; }
        else                  { s = mb2; off = local - 704; }
        biasd[local] = rdf(s, off, f32);
    }
}

// ---------------------------------------------------------------------------
// Staging row loaders: bf16 passthrough, or fp32 load + pack to bf16.
// ---------------------------------------------------------------------------
__device__ __forceinline__ uint4 ld8_bf16(const unsigned short* p) {
    return *(const uint4*)p;
}
__device__ __forceinline__ uint4 ld8_f32(const float* p) {
    float4 a = *(const float4*)(p);
    float4 b = *(const float4*)(p + 4);
    uint4 r;
    r.x = ((unsigned)f2bf(a.y) << 16) | f2bf(a.x);
    r.y = ((unsigned)f2bf(a.w) << 16) | f2bf(a.z);
    r.z = ((unsigned)f2bf(b.y) << 16) | f2bf(b.x);
    r.w = ((unsigned)f2bf(b.w) << 16) | f2bf(b.z);
    return r;
}

// ---------------------------------------------------------------------------
// Conv GEMM body: C_bf16[M][N] = bf16((X @ W) * rowscale), fp32 accum, K=256,
// 128x128 tile, 4 waves x (4x4) 16x16x32 MFMA.
// PRESCALE: multiply output row by rsqrt(outdeg[row]) so the NEXT gather is a
// pure sum (diagonal scaling commutes with the linear aggregation).  Layer-1
// cannot pre-scale (counts not final during megaA) -> gather1 keeps ESCALE.
// ---------------------------------------------------------------------------
template <bool DUALX, bool PRESCALE>
__device__ __forceinline__ void gemm_body(
        unsigned short (*Xs)[40], unsigned short (*Ws)[40],
        const void* __restrict__ Xv, const int* __restrict__ flags,
        const unsigned short* __restrict__ WT,
        const int* __restrict__ cntS,
        unsigned short* __restrict__ C,
        int bx, int by, int M, int N) {
    constexpr int K = 256;
    const int tid  = threadIdx.x;
    const int lane = tid & 63;
    const int w    = tid >> 6;
    const int wr   = (w >> 1) * 64;
    const int wc   = (w & 1) * 64;
    const int lrow = lane & 15;
    const int koff = (lane >> 4) * 8;
    const int row0 = by * 128;
    const int col0 = bx * 128;
    const bool xf32 = DUALX && (flags[0] != 0);
    const unsigned short* Xb = (const unsigned short*)Xv;
    const float* Xf = (const float*)Xv;

    const int r0 = tid >> 2, q0 = tid & 3;
    const int r1 = r0 + 64;
    const int gr0 = row0 + r0, gr1 = row0 + r1;

    uint4 xv0, xv1, wv0, wv1;
    {
        int e = q0 * 8;
        xv0 = (gr0 < M) ? (xf32 ? ld8_f32(Xf + (size_t)gr0 * K + e)
                                : ld8_bf16(Xb + (size_t)gr0 * K + e)) : zero4();
        xv1 = (gr1 < M) ? (xf32 ? ld8_f32(Xf + (size_t)gr1 * K + e)
                                : ld8_bf16(Xb + (size_t)gr1 * K + e)) : zero4();
        wv0 = *(const uint4*)(WT + (size_t)(col0 + r0) * K + e);
        wv1 = *(const uint4*)(WT + (size_t)(col0 + r1) * K + e);
    }

    f32x4 acc[4][4] = {};

    for (int k0 = 0; k0 < K; k0 += 32) {
        *(uint4*)&Xs[r0][q0 * 8] = xv0;
        *(uint4*)&Xs[r1][q0 * 8] = xv1;
        *(uint4*)&Ws[r0][q0 * 8] = wv0;
        *(uint4*)&Ws[r1][q0 * 8] = wv1;
        __syncthreads();

        const int k1 = k0 + 32;
        if (k1 < K) {
            int e = k1 + q0 * 8;
            xv0 = (gr0 < M) ? (xf32 ? ld8_f32(Xf + (size_t)gr0 * K + e)
                                    : ld8_bf16(Xb + (size_t)gr0 * K + e)) : zero4();
            xv1 = (gr1 < M) ? (xf32 ? ld8_f32(Xf + (size_t)gr1 * K + e)
                                    : ld8_bf16(Xb + (size_t)gr1 * K + e)) : zero4();
            wv0 = *(const uint4*)(WT + (size_t)(col0 + r0) * K + e);
            wv1 = *(const uint4*)(WT + (size_t)(col0 + r1) * K + e);
        }

        bfrag af[4], bv[4];
#pragma unroll
        for (int i = 0; i < 4; i++)
            af[i] = *(const bfrag*)&Xs[wr + i * 16 + lrow][koff];
#pragma unroll
        for (int j = 0; j < 4; j++)
            bv[j] = *(const bfrag*)&Ws[wc + j * 16 + lrow][koff];
#pragma unroll
        for (int i = 0; i < 4; i++)
#pragma unroll
            for (int j = 0; j < 4; j++)
                acc[i][j] = __builtin_amdgcn_mfma_f32_16x16x32_bf16(
                    af[i], bv[j], acc[i][j], 0, 0, 0);
        __syncthreads();
    }

#pragma unroll
    for (int i = 0; i < 4; i++) {
#pragma unroll
        for (int r = 0; r < 4; r++) {
            int row = row0 + wr + i * 16 + ((lane >> 4) * 4) + r;
            if (row >= M) continue;
            const float s = PRESCALE ? rsqrtf((float)max(cntS[row], 1)) : 1.0f;
#pragma unroll
            for (int j = 0; j < 4; j++) {
                int col = col0 + wc + j * 16 + lrow;
                C[(size_t)row * N + col] = f2bf(acc[i][j][r] * s);
            }
        }
    }
}

// ---------------------------------------------------------------------------
// Mega kernel A: blocks [0, GB_PLACE) = one-pass padded-CSR build (FIRST),
// blocks [GB_PLACE, GB_PLACE+GB_GEMM) = layer-1 GEMM tiles.
// WHY place-first: the scattered 2B stores into the 6.4MB esrc_pad must keep
// their dirty L2 lines resident until the ~16 stores/line all land; when the
// GEMM ran concurrently its ~100MB X-stream evicted half-filled lines ->
// refetch + multiple partial writebacks (WRITE_SIZE 96MB vs 32MB logical).
// Place blocks at low bids fill the device first with only the 6.8MB place
// working set live (fits L2) -> one writeback per line; GEMM streams after.
// ---------------------------------------------------------------------------
__launch_bounds__(256)
__global__ void megaA_kernel(const void* __restrict__ x,
                             const int* __restrict__ ei,
                             const int* __restrict__ flags,
                             const unsigned short* __restrict__ WT,
                             unsigned short* __restrict__ Hbf,
                             int* __restrict__ cntS, int* __restrict__ cntD,
                             unsigned short* __restrict__ esrc_pad, int M) {
    __shared__ unsigned short Xs[128][40];
    __shared__ unsigned short Ws[128][40];
    const int bid = blockIdx.x;
    if (bid < GB_PLACE) {
        int e = bid * 256 + threadIdx.x;
        if (e < N_EDGES) {
            int s, d; load_edge(ei, flags[1], e, s, d);
            atomicAdd(&cntS[s], 1);
            int pos = atomicAdd(&cntD[d], 1);
            if (pos < 64)
                __builtin_nontemporal_store((unsigned short)s,
                                            &esrc_pad[(d << 6) + pos]);
        }
    } else {
        const int gb = bid - GB_PLACE;
        gemm_body<true, false>(Xs, Ws, x, flags, WT, nullptr, Hbf,
                               gb & 1, gb >> 1, M, 256);
    }
}

// Plain conv GEMM (layers 2,3) with output pre-scale by rsqrt(outdeg).
__launch_bounds__(256)
__global__ void mfma_gemm_kernel(const unsigned short* __restrict__ X,
                                 const int* __restrict__ flags,
                                 const unsigned short* __restrict__ WT,
                                 const int* __restrict__ cntS,
                                 unsigned short* __restrict__ C,
                                 int M, int N) {
    __shared__ unsigned short Xs[128][40];
    __shared__ unsigned short Ws[128][40];
    gemm_body<false, true>(Xs, Ws, X, flags, WT, cntS, C,
                           blockIdx.x, blockIdx.y, M, N);
}

// ---------------------------------------------------------------------------
// Fused MLP head:  out[M][64] = relu(X[M][128] @ mW1 + mb1) @ mW2 + mb2
// ---------------------------------------------------------------------------
__launch_bounds__(256)
__global__ void mfma_mlp2_kernel(const unsigned short* __restrict__ X,
                                 const unsigned short* __restrict__ WT1, // [64][128]
                                 const unsigned short* __restrict__ WT2, // [64][64]
                                 const float* __restrict__ b1,
                                 const float* __restrict__ b2,
                                 float* __restrict__ out, int M) {
    __shared__ unsigned short Xs[128][136];
    __shared__ unsigned short W1s[64][136];
    __shared__ unsigned short W2s[64][72];
    const int tid  = threadIdx.x;
    const int lane = tid & 63;
    const int w    = tid >> 6;
    const int lrow = lane & 15;
    const int koff = (lane >> 4) * 8;
    const int row0 = blockIdx.x * 128;

#pragma unroll
    for (int i = 0; i < 8; i++) {
        int c = tid + i * 256;
        int r = c >> 4, q = c & 15;
        int gr = row0 + r;
        uint4 v = (gr < M) ? *(const uint4*)(X + (size_t)gr * 128 + q * 8) : zero4();
        *(uint4*)&Xs[r][q * 8] = v;
    }
#pragma unroll
    for (int i = 0; i < 4; i++) {
        int c = tid + i * 256;
        int n = c >> 4, q = c & 15;
        *(uint4*)&W1s[n][q * 8] = *(const uint4*)(WT1 + (size_t)n * 128 + q * 8);
    }
#pragma unroll
    for (int i = 0; i < 2; i++) {
        int c = tid + i * 256;
        int n = c >> 3, q = c & 7;
        *(uint4*)&W2s[n][q * 8] = *(const uint4*)(WT2 + (size_t)n * 64 + q * 8);
    }
    __syncthreads();

    f32x4 acc[2][4] = {};
#pragma unroll
    for (int k0 = 0; k0 < 128; k0 += 32) {
        bfrag af[2], bv[4];
#pragma unroll
        for (int i = 0; i < 2; i++)
            af[i] = *(const bfrag*)&Xs[w * 32 + i * 16 + lrow][k0 + koff];
#pragma unroll
        for (int j = 0; j < 4; j++)
            bv[j] = *(const bfrag*)&W1s[j * 16 + lrow][k0 + koff];
#pragma unroll
        for (int i = 0; i < 2; i++)
#pragma unroll
            for (int j = 0; j < 4; j++)
                acc[i][j] = __builtin_amdgcn_mfma_f32_16x16x32_bf16(
                    af[i], bv[j], acc[i][j], 0, 0, 0);
    }
    __syncthreads();

#pragma unroll
    for (int i = 0; i < 2; i++) {
#pragma unroll
        for (int r = 0; r < 4; r++) {
            int row = w * 32 + i * 16 + ((lane >> 4) * 4) + r;
#pragma unroll
            for (int j = 0; j < 4; j++) {
                int col = j * 16 + lrow;
                Xs[row][col] = f2bf(fmaxf(acc[i][j][r] + b1[col], 0.0f));
            }
        }
    }
    __syncthreads();

    f32x4 acc2[2][4] = {};
#pragma unroll
    for (int k0 = 0; k0 < 64; k0 += 32) {
        bfrag af[2], bv[4];
#pragma unroll
        for (int i = 0; i < 2; i++)
            af[i] = *(const bfrag*)&Xs[w * 32 + i * 16 + lrow][k0 + koff];
#pragma unroll
        for (int j = 0; j < 4; j++)
            bv[j] = *(const bfrag*)&W2s[j * 16 + lrow][k0 + koff];
#pragma unroll
        for (int i = 0; i < 2; i++)
#pragma unroll
            for (int j = 0; j < 4; j++)
                acc2[i][j] = __builtin_amdgcn_mfma_f32_16x16x32_bf16(
                    af[i], bv[j], acc2[i][j], 0, 0, 0);
    }

#pragma unroll
    for (int i = 0; i < 2; i++) {
#pragma unroll
        for (int r = 0; r < 4; r++) {
            int row = row0 + w * 32 + i * 16 + ((lane >> 4) * 4) + r;
            if (row >= M) continue;
#pragma unroll
            for (int j = 0; j < 4; j++) {
                int col = j * 16 + lrow;
                out[(size_t)row * 64 + col] = acc2[i][j][r] + b2[col];
            }
        }
    }
}

// ---------------------------------------------------------------------------
// Padded-CSR whole-row gather:
//   Y[n,:] = relu( sIn[n] * (Σ_e [sOut[src_e]] * H[src_e,:]) + bias )
// ESCALE=true only for layer 1 (H1 written before counts final); layers 2/3
// read pre-scaled H -> pure sum (no per-edge random cntS load).
// Unroll-8 edge loop: 8 outstanding row loads per thread to fill the per-CU
// miss queue (gather is L2-miss latency-bound, ~56% L2 hit on 25.6MB H).
// LQ = D/8 uint4-lanes per node.  OUT: 0 = bf16 only; 2 = fp32 + bf16 mirror.
// ---------------------------------------------------------------------------
__device__ __forceinline__ void accs(unsigned int u, float s, float& a0, float& a1) {
    a0 = fmaf(s, __uint_as_float(u << 16), a0);
    a1 = fmaf(s, __uint_as_float(u & 0xffff0000u), a1);
}
__device__ __forceinline__ void acc4s(uint4 u, float s, float (&a)[8]) {
    accs(u.x, s, a[0], a[1]); accs(u.y, s, a[2], a[3]);
    accs(u.z, s, a[4], a[5]); accs(u.w, s, a[6], a[7]);
}

template <int LQ, bool ESCALE, int OUT>
__launch_bounds__(256)
__global__ void gather_bf16_kernel(const int* __restrict__ cntD,
                                   const int* __restrict__ cntS,
                                   const unsigned short* __restrict__ esrc_pad,
                                   const unsigned short* __restrict__ H,
                                   const float* __restrict__ bias,
                                   float* __restrict__ Yf,
                                   unsigned short* __restrict__ Yb, int nNodes) {
    constexpr int NPB = 256 / LQ;
    constexpr int D = LQ * 8;
    const int tid = threadIdx.x;
    const int node = blockIdx.x * NPB + tid / LQ;
    const int lane = tid % LQ;
    if (node >= nNodes) return;
    const uint4* __restrict__ H4 = (const uint4*)H;
    const unsigned short* __restrict__ ep = esrc_pad + (node << 6);

    float a[8] = {};
    const int cn = min(cntD[node], 64);
    int j = 0;
    for (; j + 8 <= cn; j += 8) {
        int s[8];
#pragma unroll
        for (int t = 0; t < 8; t++) s[t] = ep[j + t];
        float w[8];
#pragma unroll
        for (int t = 0; t < 8; t++)
            w[t] = ESCALE ? rsqrtf((float)max(cntS[s[t]], 1)) : 1.0f;
        uint4 u[8];
#pragma unroll
        for (int t = 0; t < 8; t++) u[t] = H4[(size_t)s[t] * LQ + lane];
#pragma unroll
        for (int t = 0; t < 8; t++) acc4s(u[t], w[t], a);
    }
    for (; j + 4 <= cn; j += 4) {
        int s[4];
#pragma unroll
        for (int t = 0; t < 4; t++) s[t] = ep[j + t];
        float w[4];
#pragma unroll
        for (int t = 0; t < 4; t++)
            w[t] = ESCALE ? rsqrtf((float)max(cntS[s[t]], 1)) : 1.0f;
        uint4 u[4];
#pragma unroll
        for (int t = 0; t < 4; t++) u[t] = H4[(size_t)s[t] * LQ + lane];
#pragma unroll
        for (int t = 0; t < 4; t++) acc4s(u[t], w[t], a);
    }
    for (; j < cn; j++) {
        int s0 = ep[j];
        float w0 = ESCALE ? rsqrtf((float)max(cntS[s0], 1)) : 1.0f;
        uint4 u = H4[(size_t)s0 * LQ + lane];
        acc4s(u, w0, a);
    }
    const float sc = rsqrtf((float)max(cntD[node], 1));
    const float* bp = bias + lane * 8;
    float4 b0 = *(const float4*)(bp);
    float4 b1 = *(const float4*)(bp + 4);
    float r0 = fmaxf(fmaf(a[0], sc, b0.x), 0.0f);
    float r1 = fmaxf(fmaf(a[1], sc, b0.y), 0.0f);
    float r2 = fmaxf(fmaf(a[2], sc, b0.z), 0.0f);
    float r3 = fmaxf(fmaf(a[3], sc, b0.w), 0.0f);
    float r4 = fmaxf(fmaf(a[4], sc, b1.x), 0.0f);
    float r5 = fmaxf(fmaf(a[5], sc, b1.y), 0.0f);
    float r6 = fmaxf(fmaf(a[6], sc, b1.z), 0.0f);
    float r7 = fmaxf(fmaf(a[7], sc, b1.w), 0.0f);
    if (OUT == 2) {
        float* yp = Yf + (size_t)node * D + lane * 8;
        float4 o0 = {r0, r1, r2, r3};
        float4 o1 = {r4, r5, r6, r7};
        *(float4*)(yp)     = o0;
        *(float4*)(yp + 4) = o1;
    }
    {
        unsigned short* yp = Yb + (size_t)node * D + lane * 8;
        ushort4 o0, o1;
        o0.x = f2bf(r0); o0.y = f2bf(r1); o0.z = f2bf(r2); o0.w = f2bf(r3);
        o1.x = f2bf(r4); o1.y = f2bf(r5); o1.z = f2bf(r6); o1.w = f2bf(r7);
        *(ushort4*)(yp)     = o0;
        *(ushort4*)(yp + 4) = o1;
    }
}

// ---------------------------------------------------------------------------
extern "C" void kernel_launch(void* const* d_in, const int* in_sizes, int n_in,
                              void* d_out, int out_size, void* d_ws, size_t ws_size,
                              hipStream_t stream) {
    const void* x  = d_in[0];
    const int*  ei = (const int*)d_in[1];
    const void *W1 = d_in[2],  *b1 = d_in[3];
    const void *W2 = d_in[4],  *b2 = d_in[5];
    const void *W3 = d_in[6],  *b3 = d_in[7];
    const void *mW1 = d_in[8], *mb1 = d_in[9];
    const void *mW2 = d_in[10],*mb2 = d_in[11];

    // Output: fp32 concatenated (out[50000x64], h_last[50000x128])
    float* out   = (float*)d_out;
    float* out_h = out + (size_t)N_NODES * 64;

    float* ws = (float*)d_ws;
    size_t off = 0;
    int*   flags  = (int*)(ws + off); off += 64;
    int*   cntS   = (int*)(ws + off); off += N_NODES;        // zeroed together
    int*   cntD   = (int*)(ws + off); off += N_NODES;
    unsigned short* esrc_p = (unsigned short*)(ws + off);
    off += (size_t)N_NODES * 32;                             // 50000*64 ushorts
    float* biasd  = ws + off;         off += 768;
    // bias offsets: b1@0 b2@256 b3@512 mb1@640 mb2@704
    off = (off + 63) & ~(size_t)63;
    unsigned short* WT  = (unsigned short*)(ws + off); off += 88448;  // 176896 u16
    // WT segments: conv@0, mWT1@163840, mWT2@172032
    unsigned short* Gbf = (unsigned short*)(ws + off); off += (size_t)N_NODES * 128;
    unsigned short* Hbf = (unsigned short*)(ws + off); off += (size_t)N_NODES * 128;
    unsigned short* hob = (unsigned short*)(ws + off); off += (size_t)N_NODES * 64;  // h_last bf16

    const int M = N_NODES;
    const dim3 blk(256);
    const int gy128 = (M + 127) / 128;        // 391

    // 1) detect + zero counters
    detect_zero_kernel<<<391, blk, 0, stream>>>(
        (const unsigned short*)x, ei, flags, cntS);

    // 2) weight/bias conversion
    cvt_all_kernel<<<(176896 + 255) / 256, blk, 0, stream>>>(
        W1, W2, W3, mW1, mW2, b1, b2, b3, mb1, mb2, flags, WT, biasd);

    // 3) mega A: padded-CSR build (low bids, runs first) || layer-1 GEMM
    megaA_kernel<<<GB_GEMM + GB_PLACE, blk, 0, stream>>>(
        x, ei, flags, WT, Hbf, cntS, cntD, esrc_p, M);

    // 4) gather 1 (per-edge sOut; H1 unscaled) -> Gbf
    gather_bf16_kernel<32, true, 0><<<(M + 7) / 8, blk, 0, stream>>>(
        cntD, cntS, esrc_p, Hbf, biasd, nullptr, Gbf, M);

    // 5) layer 2 GEMM (output pre-scaled by rsqrt(outdeg)) + pure-sum gather
    mfma_gemm_kernel<<<dim3(2, gy128), blk, 0, stream>>>(
        Gbf, flags, WT + 65536, cntS, Hbf, M, 256);
    gather_bf16_kernel<32, false, 0><<<(M + 7) / 8, blk, 0, stream>>>(
        cntD, cntS, esrc_p, Hbf, biasd + 256, nullptr, Gbf, M);

    // 6) layer 3 GEMM (N=128, pre-scaled) + pure-sum gather -> out_h fp32 + hob bf16
    mfma_gemm_kernel<<<dim3(1, gy128), blk, 0, stream>>>(
        Gbf, flags, WT + 131072, cntS, Hbf, M, 128);
    gather_bf16_kernel<16, false, 2><<<(M + 15) / 16, blk, 0, stream>>>(
        cntD, cntS, esrc_p, Hbf, biasd + 512, out_h, hob, M);

    // 7) MLP head fused: out = relu(hob @ mW1 + mb1) @ mW2 + mb2
    mfma_mlp2_kernel<<<gy128, blk, 0, stream>>>(
        hob, WT + 163840, WT + 172032, biasd + 640, biasd + 704, out, M);
}